// Round 1
// baseline (2141.154 us; speedup 1.0000x reference)
//
#include <hip/hip_runtime.h>

#define D 128

// ---- degree: deg[r] += e and deg[s] += e over all E undirected edges ----
__global__ __launch_bounds__(256) void k_deg(
    const int* __restrict__ s, const int* __restrict__ r,
    const float* __restrict__ e, float* __restrict__ deg, int E) {
  int i = blockIdx.x * 256 + threadIdx.x;
  if (i < E) {
    float ev = e[i];
    atomicAdd(&deg[r[i]], ev);
    atomicAdd(&deg[s[i]], ev);
  }
}

// ---- dis = deg > 0 ? rsqrt(deg) : 0, in place ----
__global__ __launch_bounds__(256) void k_dis(float* __restrict__ deg, int N) {
  int i = blockIdx.x * 256 + threadIdx.x;
  if (i < N) {
    float d = deg[i];
    deg[i] = d > 0.f ? rsqrtf(d) : 0.f;
  }
}

// ---- Y = X @ W  (K = 128, 128 cols). 32 rows/block, K staged in 64-chunks. ----
__global__ __launch_bounds__(256) void k_gemm(
    const float* __restrict__ X, const float* __restrict__ W,
    float* __restrict__ Y, int nrows) {
  __shared__ float Wl[64 * D];   // 32 KB
  __shared__ float Xl[32][64];   // 8 KB
  int tid = threadIdx.x;
  int c = tid & 127;
  int g = tid >> 7;              // 0..1, each handles 16 rows
  int row0 = blockIdx.x * 32;

  float acc[16];
#pragma unroll
  for (int r = 0; r < 16; ++r) acc[r] = 0.f;

  for (int k0 = 0; k0 < D; k0 += 64) {
    for (int i = tid; i < 64 * D; i += 256)
      Wl[i] = W[(k0 + (i >> 7)) * D + (i & 127)];
    for (int i = tid; i < 32 * 64; i += 256) {
      int rr = i >> 6, dd = i & 63;
      int row = row0 + rr;
      Xl[rr][dd] = (row < nrows) ? X[(size_t)row * D + k0 + dd] : 0.f;
    }
    __syncthreads();
#pragma unroll
    for (int dd = 0; dd < 64; ++dd) {
      float w = Wl[dd * D + c];
#pragma unroll
      for (int r = 0; r < 16; ++r)
        acc[r] += Xl[g * 16 + r][dd] * w;
    }
    __syncthreads();
  }
#pragma unroll
  for (int r = 0; r < 16; ++r) {
    int row = row0 + g * 16 + r;
    if (row < nrows) Y[(size_t)row * D + c] = acc[r];
  }
}

// ---- out = nodes + b (broadcast bias), float4-vectorized ----
__global__ __launch_bounds__(256) void k_init_out(
    const float* __restrict__ nodes, const float* __restrict__ b,
    float* __restrict__ out, int n4) {
  int i = blockIdx.x * 256 + threadIdx.x;
  if (i < n4) {
    float4 v = reinterpret_cast<const float4*>(nodes)[i];
    float4 bb = reinterpret_cast<const float4*>(b)[i & 31];  // 32 float4 per row
    v.x += bb.x; v.y += bb.y; v.z += bb.z; v.w += bb.w;
    reinterpret_cast<float4*>(out)[i] = v;
  }
}

// ---- out += b ----
__global__ __launch_bounds__(256) void k_bias(
    float* __restrict__ out, const float* __restrict__ b, int n4) {
  int i = blockIdx.x * 256 + threadIdx.x;
  if (i < n4) {
    float4 v = reinterpret_cast<float4*>(out)[i];
    float4 bb = reinterpret_cast<const float4*>(b)[i & 31];
    v.x += bb.x; v.y += bb.y; v.z += bb.z; v.w += bb.w;
    reinterpret_cast<float4*>(out)[i] = v;
  }
}

// ---- edge scatter: for each directed edge (src,dst), out[dst,:] += X[src,:]*w ----
// 128 threads per edge (one per feature dim), 2 edges per 256-thread block.
__global__ __launch_bounds__(256) void k_edge(
    const int* __restrict__ senders, const int* __restrict__ receivers,
    const float* __restrict__ edges, const float* __restrict__ dis,
    const float* __restrict__ X, float* __restrict__ out, int E) {
  int t = blockIdx.x * 256 + threadIdx.x;
  int eidx = t >> 7;          // directed edge id in [0, 2E)
  int d = t & 127;
  if (eidx >= 2 * E) return;
  bool fwd = eidx < E;
  int i = fwd ? eidx : eidx - E;
  int sv = senders[i];
  int rv = receivers[i];
  int src = fwd ? sv : rv;
  int dst = fwd ? rv : sv;
  float w = dis[src] * edges[i] * dis[dst];
  float val = X[(size_t)src * D + d] * w;
  atomicAdd(&out[(size_t)dst * D + d], val);
}

extern "C" void kernel_launch(void* const* d_in, const int* in_sizes, int n_in,
                              void* d_out, int out_size, void* d_ws, size_t ws_size,
                              hipStream_t stream) {
  const float* nodes     = (const float*)d_in[0];
  const int*   senders   = (const int*)d_in[1];
  const int*   receivers = (const int*)d_in[2];
  const float* edges     = (const float*)d_in[3];
  const float* W1        = (const float*)d_in[4];
  const float* b1        = (const float*)d_in[5];
  const float* W2        = (const float*)d_in[6];
  const float* b2        = (const float*)d_in[7];
  float* out = (float*)d_out;

  int N = in_sizes[0] / D;
  int E = in_sizes[1];

  // workspace: deg/dis (N floats, rounded up), then X buffer (N*D floats)
  float* deg = (float*)d_ws;
  size_t deg_bytes = (((size_t)N * 4 + 511) / 512) * 512;
  float* X = (float*)((char*)d_ws + deg_bytes);

  hipMemsetAsync(deg, 0, (size_t)N * 4, stream);
  k_deg<<<(E + 255) / 256, 256, 0, stream>>>(senders, receivers, edges, deg, E);
  k_dis<<<(N + 255) / 256, 256, 0, stream>>>(deg, N);

  int n4 = N * D / 4;
  int gemm_blocks = (N + 31) / 32;
  int edge_blocks = (int)(((long long)2 * E * D + 255) / 256);
  int ew_blocks = (n4 + 255) / 256;

  // ---- layer 1: h1 = nodes + (Anorm @ (nodes@W1) + b1), h1 lives in d_out ----
  k_gemm<<<gemm_blocks, 256, 0, stream>>>(nodes, W1, X, N);
  k_init_out<<<ew_blocks, 256, 0, stream>>>(nodes, b1, out, n4);
  k_edge<<<edge_blocks, 256, 0, stream>>>(senders, receivers, edges, deg, X, out, E);

  // ---- layer 2: out = h1 + (Anorm @ (h1@W2) + b2) ----
  k_gemm<<<gemm_blocks, 256, 0, stream>>>(out, W2, X, N);
  k_bias<<<ew_blocks, 256, 0, stream>>>(out, b2, n4);
  k_edge<<<edge_blocks, 256, 0, stream>>>(senders, receivers, edges, deg, X, out, E);
}

// Round 2
// 1227.839 us; speedup vs baseline: 1.7438x; 1.7438x over previous
//
#include <hip/hip_runtime.h>
#include <hip/hip_bf16.h>

#define D 128

// ---- degree: deg[r] += e and deg[s] += e over all E undirected edges ----
__global__ __launch_bounds__(256) void k_deg(
    const int* __restrict__ s, const int* __restrict__ r,
    const float* __restrict__ e, float* __restrict__ deg, int E) {
  int i = blockIdx.x * 256 + threadIdx.x;
  if (i < E) {
    float ev = e[i];
    atomicAdd(&deg[r[i]], ev);
    atomicAdd(&deg[s[i]], ev);
  }
}

// ---- dis = deg > 0 ? rsqrt(deg) : 0, in place ----
__global__ __launch_bounds__(256) void k_dis(float* __restrict__ deg, int N) {
  int i = blockIdx.x * 256 + threadIdx.x;
  if (i < N) {
    float d = deg[i];
    deg[i] = d > 0.f ? rsqrtf(d) : 0.f;
  }
}

// ---- in-degree histogram over directed edges (both directions) ----
__global__ __launch_bounds__(256) void k_count(
    const int* __restrict__ s, const int* __restrict__ r,
    int* __restrict__ cnt, int E) {
  int i = blockIdx.x * 256 + threadIdx.x;
  if (i < E) {
    atomicAdd(&cnt[r[i]], 1);
    atomicAdd(&cnt[s[i]], 1);
  }
}

// ---- scan stage 1: per-2048-chunk exclusive scan + chunk totals ----
__global__ __launch_bounds__(256) void k_scan1(
    const int* __restrict__ cnt, int* __restrict__ rowptr,
    int* __restrict__ chsum, int N) {
  __shared__ int ts[256];
  int tid = threadIdx.x;
  int base = blockIdx.x * 2048 + tid * 8;
  int v[8];
  int run = 0;
#pragma unroll
  for (int j = 0; j < 8; ++j) {
    int idx = base + j;
    int t = (idx < N) ? cnt[idx] : 0;
    v[j] = run;       // thread-local exclusive
    run += t;
  }
  ts[tid] = run;
  __syncthreads();
  for (int off = 1; off < 256; off <<= 1) {
    int t = (tid >= off) ? ts[tid - off] : 0;
    __syncthreads();
    ts[tid] += t;
    __syncthreads();
  }
  int excl = ts[tid] - run;  // exclusive prefix of this thread within chunk
#pragma unroll
  for (int j = 0; j < 8; ++j) {
    int idx = base + j;
    if (idx < N) rowptr[idx] = excl + v[j];
  }
  if (tid == 255) chsum[blockIdx.x] = ts[255];
}

// ---- scan stage 2: serial exclusive scan of ~49 chunk sums ----
__global__ __launch_bounds__(64) void k_scan2(int* __restrict__ chsum, int nch) {
  if (threadIdx.x == 0) {
    int run = 0;
    for (int i = 0; i < nch; ++i) { int t = chsum[i]; chsum[i] = run; run += t; }
    chsum[nch] = run;
  }
}

// ---- scan stage 3: add chunk offsets; init cursor; write rowptr[N] ----
__global__ __launch_bounds__(256) void k_scan3(
    int* __restrict__ rowptr, int* __restrict__ cursor,
    const int* __restrict__ chsum, int N, int nch) {
  int i = blockIdx.x * 256 + threadIdx.x;
  if (i < N) {
    int v = rowptr[i] + chsum[i >> 11];
    rowptr[i] = v;
    cursor[i] = v;
  } else if (i == N) {
    rowptr[N] = chsum[nch];
  }
}

// ---- fill CSR entries {src, w}; w = dis[s]*e*dis[r] is direction-symmetric ----
__global__ __launch_bounds__(256) void k_fill(
    const int* __restrict__ s, const int* __restrict__ r,
    const float* __restrict__ e, const float* __restrict__ dis,
    int* __restrict__ cursor, int2* __restrict__ ent, int E) {
  int i = blockIdx.x * 256 + threadIdx.x;
  if (i >= E) return;
  int sv = s[i], rv = r[i];
  float w = dis[sv] * e[i] * dis[rv];
  int wy = __float_as_int(w);
  int p1 = atomicAdd(&cursor[rv], 1);
  ent[p1] = make_int2(sv, wy);
  int p2 = atomicAdd(&cursor[sv], 1);
  ent[p2] = make_int2(rv, wy);
}

// ---- Y = X @ W (K=128), fp32 compute, bf16 output. 32 rows/block. ----
__global__ __launch_bounds__(256) void k_gemm(
    const float* __restrict__ X, const float* __restrict__ W,
    __hip_bfloat16* __restrict__ Y, int nrows) {
  __shared__ float Wl[64 * D];   // 32 KB
  __shared__ float Xl[32][64];   // 8 KB
  int tid = threadIdx.x;
  int c = tid & 127;
  int g = tid >> 7;              // 0..1, each handles 16 rows
  int row0 = blockIdx.x * 32;

  float acc[16];
#pragma unroll
  for (int r = 0; r < 16; ++r) acc[r] = 0.f;

  for (int k0 = 0; k0 < D; k0 += 64) {
    for (int i = tid; i < 64 * D; i += 256)
      Wl[i] = W[(k0 + (i >> 7)) * D + (i & 127)];
    for (int i = tid; i < 32 * 64; i += 256) {
      int rr = i >> 6, dd = i & 63;
      int row = row0 + rr;
      Xl[rr][dd] = (row < nrows) ? X[(size_t)row * D + k0 + dd] : 0.f;
    }
    __syncthreads();
#pragma unroll
    for (int dd = 0; dd < 64; ++dd) {
      float w = Wl[dd * D + c];
#pragma unroll
      for (int r = 0; r < 16; ++r)
        acc[r] += Xl[g * 16 + r][dd] * w;
    }
    __syncthreads();
  }
#pragma unroll
  for (int r = 0; r < 16; ++r) {
    int row = row0 + g * 16 + r;
    if (row < nrows) Y[(size_t)row * D + c] = __float2bfloat16(acc[r]);
  }
}

// ---- gather-aggregate: one 64-lane wave per node, 2 dims/lane (bf16x2) ----
// out[v,:] = prev[v,:] + b[:] + sum_{edges into v} X[src,:] * w
__global__ __launch_bounds__(256) void k_agg(
    const int* __restrict__ rowptr, const int2* __restrict__ ent,
    const unsigned int* __restrict__ X2, const float* __restrict__ prev,
    const float* __restrict__ bias, float* __restrict__ out, int N) {
  int node = blockIdx.x * 4 + (threadIdx.x >> 6);
  int lane = threadIdx.x & 63;
  if (node >= N) return;
  float2 acc = reinterpret_cast<const float2*>(prev)[(size_t)node * 64 + lane];
  float2 bb = reinterpret_cast<const float2*>(bias)[lane];
  acc.x += bb.x; acc.y += bb.y;
  int beg = rowptr[node], end = rowptr[node + 1];
  for (int j = beg; j < end; ++j) {
    int2 eJ = ent[j];
    float w = __int_as_float(eJ.y);
    unsigned int xz = X2[(size_t)eJ.x * 64 + lane];
    acc.x = fmaf(__uint_as_float(xz << 16), w, acc.x);
    acc.y = fmaf(__uint_as_float(xz & 0xffff0000u), w, acc.y);
  }
  reinterpret_cast<float2*>(out)[(size_t)node * 64 + lane] = acc;
}

extern "C" void kernel_launch(void* const* d_in, const int* in_sizes, int n_in,
                              void* d_out, int out_size, void* d_ws, size_t ws_size,
                              hipStream_t stream) {
  const float* nodes     = (const float*)d_in[0];
  const int*   senders   = (const int*)d_in[1];
  const int*   receivers = (const int*)d_in[2];
  const float* edges     = (const float*)d_in[3];
  const float* W1        = (const float*)d_in[4];
  const float* b1        = (const float*)d_in[5];
  const float* W2        = (const float*)d_in[6];
  const float* b2        = (const float*)d_in[7];
  float* out = (float*)d_out;

  int N = in_sizes[0] / D;
  int E = in_sizes[1];
  int NCH = (N + 2047) / 2048;

  // workspace layout (512-B aligned slabs)
  auto alignup = [](size_t x) { return (x + 511) / 512 * 512; };
  char* p = (char*)d_ws;
  float* deg    = (float*)p; p += alignup((size_t)N * 4);
  int*   cnt    = (int*)p;   p += alignup((size_t)N * 4);
  int*   rowptr = (int*)p;   p += alignup(((size_t)N + 1) * 4);
  int*   cursor = (int*)p;   p += alignup((size_t)N * 4);
  int*   chsum  = (int*)p;   p += alignup(((size_t)NCH + 1) * 4);
  int2*  ent    = (int2*)p;  p += alignup((size_t)2 * E * 8);
  __hip_bfloat16* X = (__hip_bfloat16*)p;  // N*D bf16 = 25.6 MB

  hipMemsetAsync(deg, 0, (size_t)N * 4, stream);
  hipMemsetAsync(cnt, 0, (size_t)N * 4, stream);

  int eb = (E + 255) / 256;
  k_deg<<<eb, 256, 0, stream>>>(senders, receivers, edges, deg, E);
  k_dis<<<(N + 255) / 256, 256, 0, stream>>>(deg, N);

  // CSR build (shared by both layers)
  k_count<<<eb, 256, 0, stream>>>(senders, receivers, cnt, E);
  k_scan1<<<NCH, 256, 0, stream>>>(cnt, rowptr, chsum, N);
  k_scan2<<<1, 64, 0, stream>>>(chsum, NCH);
  k_scan3<<<(N + 1 + 255) / 256, 256, 0, stream>>>(rowptr, cursor, chsum, N, NCH);
  k_fill<<<eb, 256, 0, stream>>>(senders, receivers, edges, deg, cursor, ent, E);

  int gemm_blocks = (N + 31) / 32;
  int agg_blocks = (N + 3) / 4;

  // ---- layer 1: out = nodes + b1 + Agg(nodes @ W1) ----
  k_gemm<<<gemm_blocks, 256, 0, stream>>>(nodes, W1, X, N);
  k_agg<<<agg_blocks, 256, 0, stream>>>(rowptr, ent, (const unsigned int*)X,
                                        nodes, b1, out, N);

  // ---- layer 2: out = h1 + b2 + Agg(h1 @ W2), h1 = out (in-place safe) ----
  k_gemm<<<gemm_blocks, 256, 0, stream>>>(out, W2, X, N);
  k_agg<<<agg_blocks, 256, 0, stream>>>(rowptr, ent, (const unsigned int*)X,
                                        out, b2, out, N);
}

// Round 4
// 717.677 us; speedup vs baseline: 2.9835x; 1.7109x over previous
//
#include <hip/hip_runtime.h>
#include <hip/hip_bf16.h>

#define D 128

typedef __attribute__((ext_vector_type(8))) short bf16x8;
typedef __attribute__((ext_vector_type(4))) float f32x4;

static __device__ __forceinline__ short f2bf(float f) {
  __hip_bfloat16 h = __float2bfloat16(f);
  return *reinterpret_cast<short*>(&h);
}

// ---- degree: deg[r] += e and deg[s] += e over all E undirected edges ----
__global__ __launch_bounds__(256) void k_deg(
    const int* __restrict__ s, const int* __restrict__ r,
    const float* __restrict__ e, float* __restrict__ deg, int E) {
  int i = blockIdx.x * 256 + threadIdx.x;
  if (i < E) {
    float ev = e[i];
    atomicAdd(&deg[r[i]], ev);
    atomicAdd(&deg[s[i]], ev);
  }
}

// ---- dis = deg > 0 ? rsqrt(deg) : 0, in place ----
__global__ __launch_bounds__(256) void k_dis(float* __restrict__ deg, int N) {
  int i = blockIdx.x * 256 + threadIdx.x;
  if (i < N) {
    float d = deg[i];
    deg[i] = d > 0.f ? rsqrtf(d) : 0.f;
  }
}

// ---- in-degree histogram over directed edges (both directions) ----
__global__ __launch_bounds__(256) void k_count(
    const int* __restrict__ s, const int* __restrict__ r,
    int* __restrict__ cnt, int E) {
  int i = blockIdx.x * 256 + threadIdx.x;
  if (i < E) {
    atomicAdd(&cnt[r[i]], 1);
    atomicAdd(&cnt[s[i]], 1);
  }
}

// ---- scan stage 1: per-2048-chunk exclusive scan + chunk totals ----
__global__ __launch_bounds__(256) void k_scan1(
    const int* __restrict__ cnt, int* __restrict__ rowptr,
    int* __restrict__ chsum, int N) {
  __shared__ int ts[256];
  int tid = threadIdx.x;
  int base = blockIdx.x * 2048 + tid * 8;
  int v[8];
  int run = 0;
#pragma unroll
  for (int j = 0; j < 8; ++j) {
    int idx = base + j;
    int t = (idx < N) ? cnt[idx] : 0;
    v[j] = run;
    run += t;
  }
  ts[tid] = run;
  __syncthreads();
  for (int off = 1; off < 256; off <<= 1) {
    int t = (tid >= off) ? ts[tid - off] : 0;
    __syncthreads();
    ts[tid] += t;
    __syncthreads();
  }
  int excl = ts[tid] - run;
#pragma unroll
  for (int j = 0; j < 8; ++j) {
    int idx = base + j;
    if (idx < N) rowptr[idx] = excl + v[j];
  }
  if (tid == 255) chsum[blockIdx.x] = ts[255];
}

// ---- scan stage 2: serial exclusive scan of chunk sums ----
__global__ __launch_bounds__(64) void k_scan2(int* __restrict__ chsum, int nch) {
  if (threadIdx.x == 0) {
    int run = 0;
    for (int i = 0; i < nch; ++i) { int t = chsum[i]; chsum[i] = run; run += t; }
    chsum[nch] = run;
  }
}

// ---- scan stage 3: add chunk offsets; init cursor; write rowptr[N] ----
__global__ __launch_bounds__(256) void k_scan3(
    int* __restrict__ rowptr, int* __restrict__ cursor,
    const int* __restrict__ chsum, int N, int nch) {
  int i = blockIdx.x * 256 + threadIdx.x;
  if (i < N) {
    int v = rowptr[i] + chsum[i >> 11];
    rowptr[i] = v;
    cursor[i] = v;
  } else if (i == N) {
    rowptr[N] = chsum[nch];
  }
}

// ---- fill CSR entries {src, w}; w = dis[s]*e*dis[r] is direction-symmetric ----
__global__ __launch_bounds__(256) void k_fill(
    const int* __restrict__ s, const int* __restrict__ r,
    const float* __restrict__ e, const float* __restrict__ dis,
    int* __restrict__ cursor, int2* __restrict__ ent, int E) {
  int i = blockIdx.x * 256 + threadIdx.x;
  if (i >= E) return;
  int sv = s[i], rv = r[i];
  float w = dis[sv] * e[i] * dis[rv];
  int wy = __float_as_int(w);
  int p1 = atomicAdd(&cursor[rv], 1);
  ent[p1] = make_int2(sv, wy);
  int p2 = atomicAdd(&cursor[sv], 1);
  ent[p2] = make_int2(rv, wy);
}

// ---- W prep: Wt[col*128 + k] = bf16(W[k][col])  (transpose + quantize) ----
__global__ __launch_bounds__(256) void k_wprep(
    const float* __restrict__ W, unsigned short* __restrict__ Wt) {
  int idx = blockIdx.x * 256 + threadIdx.x;   // idx = col*128 + k
  int col = idx >> 7, k = idx & 127;
  Wt[idx] = (unsigned short)f2bf(W[k * D + col]);
}

// ---- Y = bf16(X @ W) via MFMA. Block: 64 rows x 128 cols, 4 waves. ----
// Wt (bf16, [col][k]) staged in LDS with 16B-chunk XOR swizzle.
__global__ __launch_bounds__(256) void k_gemm_mfma(
    const float* __restrict__ X, const unsigned short* __restrict__ Wt,
    unsigned short* __restrict__ Y, int nrows) {
  __shared__ unsigned short wl[128 * 128];  // 32 KB, swizzled
  int tid = threadIdx.x;
  {
    const int4* src = reinterpret_cast<const int4*>(Wt);
#pragma unroll
    for (int j = 0; j < 8; ++j) {
      int c = tid + 256 * j;            // 16B chunk id, 2048 total
      int4 v = src[c];
      int byte = c * 16;
      int col = byte >> 8;              // row stride 256 B
      int swz = byte ^ ((col & 7) << 4);
      *reinterpret_cast<int4*>(reinterpret_cast<char*>(wl) + swz) = v;
    }
  }
  __syncthreads();

  int lane = tid & 63;
  int wv = tid >> 6;                    // wave 0..3
  int lr = lane & 15;
  int kgrp = lane >> 4;                 // 0..3
  int row = blockIdx.x * 64 + wv * 16 + lr;
  bool valid = row < nrows;

  f32x4 acc[8];
#pragma unroll
  for (int n = 0; n < 8; ++n) acc[n] = (f32x4){0.f, 0.f, 0.f, 0.f};

#pragma unroll
  for (int ks = 0; ks < 4; ++ks) {
    bf16x8 a;
    if (valid) {
      const float4* xp = reinterpret_cast<const float4*>(
          X + (size_t)row * D + ks * 32 + kgrp * 8);
      float4 f0 = xp[0], f1 = xp[1];
      a[0] = f2bf(f0.x); a[1] = f2bf(f0.y); a[2] = f2bf(f0.z); a[3] = f2bf(f0.w);
      a[4] = f2bf(f1.x); a[5] = f2bf(f1.y); a[6] = f2bf(f1.z); a[7] = f2bf(f1.w);
    } else {
      a = (bf16x8){0, 0, 0, 0, 0, 0, 0, 0};
    }
#pragma unroll
    for (int n = 0; n < 8; ++n) {
      int col = n * 16 + lr;
      int byte = col * 256 + ks * 64 + kgrp * 16;
      int swz = byte ^ ((col & 7) << 4);
      bf16x8 b = *reinterpret_cast<const bf16x8*>(
          reinterpret_cast<const char*>(wl) + swz);
      acc[n] = __builtin_amdgcn_mfma_f32_16x16x32_bf16(a, b, acc[n], 0, 0, 0);
    }
  }

  // C/D layout: D[(lane>>4)*4 + i][lane&15] in acc[n][i]
  int r0 = blockIdx.x * 64 + wv * 16 + kgrp * 4;
#pragma unroll
  for (int n = 0; n < 8; ++n) {
    int col = n * 16 + lr;
#pragma unroll
    for (int i = 0; i < 4; ++i) {
      int rr = r0 + i;
      if (rr < nrows) Y[(size_t)rr * D + col] = (unsigned short)f2bf(acc[n][i]);
    }
  }
}

// ---- gather-aggregate: one 64-lane wave per node, 2 dims/lane (bf16x2) ----
// out[v,:] = prev[v,:] + b[:] + sum_{edges into v} X[src,:] * w
__global__ __launch_bounds__(256) void k_agg(
    const int* __restrict__ rowptr, const int2* __restrict__ ent,
    const unsigned int* __restrict__ X2, const float* __restrict__ prev,
    const float* __restrict__ bias, float* __restrict__ out, int N) {
  int node = blockIdx.x * 4 + (threadIdx.x >> 6);
  int lane = threadIdx.x & 63;
  if (node >= N) return;
  float2 acc = reinterpret_cast<const float2*>(prev)[(size_t)node * 64 + lane];
  float2 bb = reinterpret_cast<const float2*>(bias)[lane];
  acc.x += bb.x; acc.y += bb.y;
  int beg = rowptr[node], end = rowptr[node + 1];
  for (int j = beg; j < end; ++j) {
    int2 eJ = ent[j];
    float w = __int_as_float(eJ.y);
    unsigned int xz = X2[(size_t)eJ.x * 64 + lane];
    acc.x = fmaf(__uint_as_float(xz << 16), w, acc.x);
    acc.y = fmaf(__uint_as_float(xz & 0xffff0000u), w, acc.y);
  }
  reinterpret_cast<float2*>(out)[(size_t)node * 64 + lane] = acc;
}

extern "C" void kernel_launch(void* const* d_in, const int* in_sizes, int n_in,
                              void* d_out, int out_size, void* d_ws, size_t ws_size,
                              hipStream_t stream) {
  const float* nodes     = (const float*)d_in[0];
  const int*   senders   = (const int*)d_in[1];
  const int*   receivers = (const int*)d_in[2];
  const float* edges     = (const float*)d_in[3];
  const float* W1        = (const float*)d_in[4];
  const float* b1        = (const float*)d_in[5];
  const float* W2        = (const float*)d_in[6];
  const float* b2        = (const float*)d_in[7];
  float* out = (float*)d_out;

  int N = in_sizes[0] / D;
  int E = in_sizes[1];
  int NCH = (N + 2047) / 2048;

  // workspace layout (512-B aligned slabs)
  auto alignup = [](size_t x) { return (x + 511) / 512 * 512; };
  char* p = (char*)d_ws;
  float* deg    = (float*)p; p += alignup((size_t)N * 4);
  int*   cnt    = (int*)p;   p += alignup((size_t)N * 4);
  int*   rowptr = (int*)p;   p += alignup(((size_t)N + 1) * 4);
  int*   cursor = (int*)p;   p += alignup((size_t)N * 4);
  int*   chsum  = (int*)p;   p += alignup(((size_t)NCH + 1) * 4);
  int2*  ent    = (int2*)p;  p += alignup((size_t)2 * E * 8);
  unsigned short* Wt1 = (unsigned short*)p; p += alignup((size_t)D * D * 2);
  unsigned short* Wt2 = (unsigned short*)p; p += alignup((size_t)D * D * 2);
  unsigned short* X   = (unsigned short*)p;  // N*D bf16 = 25.6 MB

  hipMemsetAsync(deg, 0, (size_t)N * 4, stream);
  hipMemsetAsync(cnt, 0, (size_t)N * 4, stream);

  int eb = (E + 255) / 256;
  k_deg<<<eb, 256, 0, stream>>>(senders, receivers, edges, deg, E);
  k_dis<<<(N + 255) / 256, 256, 0, stream>>>(deg, N);

  // CSR build (shared by both layers)
  k_count<<<eb, 256, 0, stream>>>(senders, receivers, cnt, E);
  k_scan1<<<NCH, 256, 0, stream>>>(cnt, rowptr, chsum, N);
  k_scan2<<<1, 64, 0, stream>>>(chsum, NCH);
  k_scan3<<<(N + 1 + 255) / 256, 256, 0, stream>>>(rowptr, cursor, chsum, N, NCH);
  k_fill<<<eb, 256, 0, stream>>>(senders, receivers, edges, deg, cursor, ent, E);

  // weight prep (bf16, transposed)
  k_wprep<<<(D * D) / 256, 256, 0, stream>>>(W1, Wt1);
  k_wprep<<<(D * D) / 256, 256, 0, stream>>>(W2, Wt2);

  int gemm_blocks = (N + 63) / 64;
  int agg_blocks = (N + 3) / 4;

  // ---- layer 1: out = nodes + b1 + Agg(nodes @ W1) ----
  k_gemm_mfma<<<gemm_blocks, 256, 0, stream>>>(nodes, Wt1, X, N);
  k_agg<<<agg_blocks, 256, 0, stream>>>(rowptr, ent, (const unsigned int*)X,
                                        nodes, b1, out, N);

  // ---- layer 2: out = h1 + b2 + Agg(h1 @ W2), h1 = out (in-place safe) ----
  k_gemm_mfma<<<gemm_blocks, 256, 0, stream>>>(out, Wt2, X, N);
  k_agg<<<agg_blocks, 256, 0, stream>>>(rowptr, ent, (const unsigned int*)X,
                                        out, b2, out, N);
}

// Round 5
// 533.455 us; speedup vs baseline: 4.0138x; 1.3453x over previous
//
#include <hip/hip_runtime.h>
#include <hip/hip_bf16.h>

#define D 128

typedef __attribute__((ext_vector_type(8))) short bf16x8;
typedef __attribute__((ext_vector_type(4))) float f32x4;

static __device__ __forceinline__ short f2bf(float f) {
  __hip_bfloat16 h = __float2bfloat16(f);
  return *reinterpret_cast<short*>(&h);
}

// ---- degree (weighted) + in-degree count, one pass over edges ----
__global__ __launch_bounds__(256) void k_degcnt(
    const int* __restrict__ s, const int* __restrict__ r,
    const float* __restrict__ e, float* __restrict__ deg,
    int* __restrict__ cnt, int E) {
  int i = blockIdx.x * 256 + threadIdx.x;
  if (i < E) {
    int sv = s[i], rv = r[i];
    float ev = e[i];
    atomicAdd(&deg[rv], ev);
    atomicAdd(&deg[sv], ev);
    atomicAdd(&cnt[rv], 1);
    atomicAdd(&cnt[sv], 1);
  }
}

// ---- dis = deg > 0 ? rsqrt(deg) : 0, in place ----
__global__ __launch_bounds__(256) void k_dis(float* __restrict__ deg, int N) {
  int i = blockIdx.x * 256 + threadIdx.x;
  if (i < N) {
    float d = deg[i];
    deg[i] = d > 0.f ? rsqrtf(d) : 0.f;
  }
}

// ---- scan stage 1: per-2048-chunk exclusive scan + chunk totals ----
__global__ __launch_bounds__(256) void k_scan1(
    const int* __restrict__ cnt, int* __restrict__ rowptr,
    int* __restrict__ chsum, int N) {
  __shared__ int ts[256];
  int tid = threadIdx.x;
  int base = blockIdx.x * 2048 + tid * 8;
  int v[8];
  int run = 0;
#pragma unroll
  for (int j = 0; j < 8; ++j) {
    int idx = base + j;
    int t = (idx < N) ? cnt[idx] : 0;
    v[j] = run;
    run += t;
  }
  ts[tid] = run;
  __syncthreads();
  for (int off = 1; off < 256; off <<= 1) {
    int t = (tid >= off) ? ts[tid - off] : 0;
    __syncthreads();
    ts[tid] += t;
    __syncthreads();
  }
  int excl = ts[tid] - run;
#pragma unroll
  for (int j = 0; j < 8; ++j) {
    int idx = base + j;
    if (idx < N) rowptr[idx] = excl + v[j];
  }
  if (tid == 255) chsum[blockIdx.x] = ts[255];
}

// ---- scan stage 2: serial exclusive scan of chunk sums ----
__global__ __launch_bounds__(64) void k_scan2(int* __restrict__ chsum, int nch) {
  if (threadIdx.x == 0) {
    int run = 0;
    for (int i = 0; i < nch; ++i) { int t = chsum[i]; chsum[i] = run; run += t; }
    chsum[nch] = run;
  }
}

// ---- scan stage 3: add chunk offsets; init cursor; write rowptr[N] ----
__global__ __launch_bounds__(256) void k_scan3(
    int* __restrict__ rowptr, int* __restrict__ cursor,
    const int* __restrict__ chsum, int N, int nch) {
  int i = blockIdx.x * 256 + threadIdx.x;
  if (i < N) {
    int v = rowptr[i] + chsum[i >> 11];
    rowptr[i] = v;
    cursor[i] = v;
  } else if (i == N) {
    rowptr[N] = chsum[nch];
  }
}

// ---- fill CSR entries {src, w}; w = dis[s]*e*dis[r] is direction-symmetric ----
__global__ __launch_bounds__(256) void k_fill(
    const int* __restrict__ s, const int* __restrict__ r,
    const float* __restrict__ e, const float* __restrict__ dis,
    int* __restrict__ cursor, int2* __restrict__ ent, int E) {
  int i = blockIdx.x * 256 + threadIdx.x;
  if (i >= E) return;
  int sv = s[i], rv = r[i];
  float w = dis[sv] * e[i] * dis[rv];
  int wy = __float_as_int(w);
  int p1 = atomicAdd(&cursor[rv], 1);
  ent[p1] = make_int2(sv, wy);
  int p2 = atomicAdd(&cursor[sv], 1);
  ent[p2] = make_int2(rv, wy);
}

// ---- W prep for both layers: Wt[col*128+k] = bf16(W[k][col]) ----
__global__ __launch_bounds__(256) void k_wprep2(
    const float* __restrict__ W1, const float* __restrict__ W2,
    unsigned short* __restrict__ Wt1, unsigned short* __restrict__ Wt2) {
  int idx = blockIdx.x * 256 + threadIdx.x;   // 0 .. 2*D*D
  const float* W = (idx < D * D) ? W1 : W2;
  unsigned short* Wt = (idx < D * D) ? Wt1 : Wt2;
  int t = idx & (D * D - 1);
  int col = t >> 7, k = t & 127;
  Wt[t] = (unsigned short)f2bf(W[k * D + col]);
}

// ---- Y = bf16(X @ W) via MFMA. Block: 64 rows x 128 cols, 4 waves. ----
__global__ __launch_bounds__(256) void k_gemm_mfma(
    const float* __restrict__ X, const unsigned short* __restrict__ Wt,
    unsigned short* __restrict__ Y, int nrows) {
  __shared__ unsigned short wl[128 * 128];  // 32 KB, swizzled
  int tid = threadIdx.x;
  {
    const int4* src = reinterpret_cast<const int4*>(Wt);
#pragma unroll
    for (int j = 0; j < 8; ++j) {
      int c = tid + 256 * j;            // 16B chunk id, 2048 total
      int4 v = src[c];
      int byte = c * 16;
      int col = byte >> 8;              // row stride 256 B
      int swz = byte ^ ((col & 7) << 4);
      *reinterpret_cast<int4*>(reinterpret_cast<char*>(wl) + swz) = v;
    }
  }
  __syncthreads();

  int lane = tid & 63;
  int wv = tid >> 6;                    // wave 0..3
  int lr = lane & 15;
  int kgrp = lane >> 4;                 // 0..3
  int row = blockIdx.x * 64 + wv * 16 + lr;
  bool valid = row < nrows;

  f32x4 acc[8];
#pragma unroll
  for (int n = 0; n < 8; ++n) acc[n] = (f32x4){0.f, 0.f, 0.f, 0.f};

#pragma unroll
  for (int ks = 0; ks < 4; ++ks) {
    bf16x8 a;
    if (valid) {
      const float4* xp = reinterpret_cast<const float4*>(
          X + (size_t)row * D + ks * 32 + kgrp * 8);
      float4 f0 = xp[0], f1 = xp[1];
      a[0] = f2bf(f0.x); a[1] = f2bf(f0.y); a[2] = f2bf(f0.z); a[3] = f2bf(f0.w);
      a[4] = f2bf(f1.x); a[5] = f2bf(f1.y); a[6] = f2bf(f1.z); a[7] = f2bf(f1.w);
    } else {
      a = (bf16x8){0, 0, 0, 0, 0, 0, 0, 0};
    }
#pragma unroll
    for (int n = 0; n < 8; ++n) {
      int col = n * 16 + lr;
      int byte = col * 256 + ks * 64 + kgrp * 16;
      int swz = byte ^ ((col & 7) << 4);
      bf16x8 b = *reinterpret_cast<const bf16x8*>(
          reinterpret_cast<const char*>(wl) + swz);
      acc[n] = __builtin_amdgcn_mfma_f32_16x16x32_bf16(a, b, acc[n], 0, 0, 0);
    }
  }

  // C/D layout: D[(lane>>4)*4 + i][lane&15] in acc[n][i]
  int r0 = blockIdx.x * 64 + wv * 16 + kgrp * 4;
#pragma unroll
  for (int n = 0; n < 8; ++n) {
    int col = n * 16 + lr;
#pragma unroll
    for (int i = 0; i < 4; ++i) {
      int rr = r0 + i;
      if (rr < nrows) Y[(size_t)rr * D + col] = (unsigned short)f2bf(acc[n][i]);
    }
  }
}

// ---- gather-aggregate: one 64-lane wave per node, 2 dims/lane (bf16x2) ----
// out[v,:] = prev[v,:] + b[:] + sum_{edges into v} X[src,:] * w
// Edge loop unrolled x8: batch ent loads, then 8 independent gathers (MLP).
__global__ __launch_bounds__(256) void k_agg(
    const int* __restrict__ rowptr, const int2* __restrict__ ent,
    const unsigned int* __restrict__ X2, const float* __restrict__ prev,
    const float* __restrict__ bias, float* __restrict__ out, int N) {
  int node = blockIdx.x * 4 + (threadIdx.x >> 6);
  int lane = threadIdx.x & 63;
  if (node >= N) return;
  float2 acc = reinterpret_cast<const float2*>(prev)[(size_t)node * 64 + lane];
  float2 bb = reinterpret_cast<const float2*>(bias)[lane];
  acc.x += bb.x; acc.y += bb.y;
  int beg = rowptr[node], end = rowptr[node + 1];
  int j = beg;
  for (; j + 8 <= end; j += 8) {
    int2 ee[8];
#pragma unroll
    for (int u = 0; u < 8; ++u) ee[u] = ent[j + u];
    unsigned int xz[8];
#pragma unroll
    for (int u = 0; u < 8; ++u) xz[u] = X2[(size_t)ee[u].x * 64 + lane];
#pragma unroll
    for (int u = 0; u < 8; ++u) {
      float w = __int_as_float(ee[u].y);
      acc.x = fmaf(__uint_as_float(xz[u] << 16), w, acc.x);
      acc.y = fmaf(__uint_as_float(xz[u] & 0xffff0000u), w, acc.y);
    }
  }
  for (; j < end; ++j) {
    int2 eJ = ent[j];
    float w = __int_as_float(eJ.y);
    unsigned int xz = X2[(size_t)eJ.x * 64 + lane];
    acc.x = fmaf(__uint_as_float(xz << 16), w, acc.x);
    acc.y = fmaf(__uint_as_float(xz & 0xffff0000u), w, acc.y);
  }
  reinterpret_cast<float2*>(out)[(size_t)node * 64 + lane] = acc;
}

extern "C" void kernel_launch(void* const* d_in, const int* in_sizes, int n_in,
                              void* d_out, int out_size, void* d_ws, size_t ws_size,
                              hipStream_t stream) {
  const float* nodes     = (const float*)d_in[0];
  const int*   senders   = (const int*)d_in[1];
  const int*   receivers = (const int*)d_in[2];
  const float* edges     = (const float*)d_in[3];
  const float* W1        = (const float*)d_in[4];
  const float* b1        = (const float*)d_in[5];
  const float* W2        = (const float*)d_in[6];
  const float* b2        = (const float*)d_in[7];
  float* out = (float*)d_out;

  int N = in_sizes[0] / D;
  int E = in_sizes[1];
  int NCH = (N + 2047) / 2048;

  // workspace layout (512-B aligned slabs)
  auto alignup = [](size_t x) { return (x + 511) / 512 * 512; };
  char* p = (char*)d_ws;
  float* deg    = (float*)p; p += alignup((size_t)N * 4);
  int*   cnt    = (int*)p;   p += alignup((size_t)N * 4);
  int*   rowptr = (int*)p;   p += alignup(((size_t)N + 1) * 4);
  int*   cursor = (int*)p;   p += alignup((size_t)N * 4);
  int*   chsum  = (int*)p;   p += alignup(((size_t)NCH + 1) * 4);
  int2*  ent    = (int2*)p;  p += alignup((size_t)2 * E * 8);
  unsigned short* Wt1 = (unsigned short*)p; p += alignup((size_t)D * D * 2);
  unsigned short* Wt2 = (unsigned short*)p; p += alignup((size_t)D * D * 2);
  unsigned short* X   = (unsigned short*)p;  // N*D bf16 = 25.6 MB

  hipMemsetAsync(deg, 0, (size_t)N * 4, stream);
  hipMemsetAsync(cnt, 0, (size_t)N * 4, stream);

  int eb = (E + 255) / 256;
  k_degcnt<<<eb, 256, 0, stream>>>(senders, receivers, edges, deg, cnt, E);
  k_dis<<<(N + 255) / 256, 256, 0, stream>>>(deg, N);

  // CSR build (shared by both layers)
  k_scan1<<<NCH, 256, 0, stream>>>(cnt, rowptr, chsum, N);
  k_scan2<<<1, 64, 0, stream>>>(chsum, NCH);
  k_scan3<<<(N + 1 + 255) / 256, 256, 0, stream>>>(rowptr, cursor, chsum, N, NCH);
  k_fill<<<eb, 256, 0, stream>>>(senders, receivers, edges, deg, cursor, ent, E);

  // weight prep (bf16, transposed), both layers in one launch
  k_wprep2<<<(2 * D * D) / 256, 256, 0, stream>>>(W1, W2, Wt1, Wt2);

  int gemm_blocks = (N + 63) / 64;
  int agg_blocks = (N + 3) / 4;

  // ---- layer 1: out = nodes + b1 + Agg(nodes @ W1) ----
  k_gemm_mfma<<<gemm_blocks, 256, 0, stream>>>(nodes, Wt1, X, N);
  k_agg<<<agg_blocks, 256, 0, stream>>>(rowptr, ent, (const unsigned int*)X,
                                        nodes, b1, out, N);

  // ---- layer 2: out = h1 + b2 + Agg(h1 @ W2), h1 = out (in-place safe) ----
  k_gemm_mfma<<<gemm_blocks, 256, 0, stream>>>(out, Wt2, X, N);
  k_agg<<<agg_blocks, 256, 0, stream>>>(rowptr, ent, (const unsigned int*)X,
                                        out, b2, out, N);
}